// Round 5
// baseline (282.031 us; speedup 1.0000x reference)
//
#include <hip/hip_runtime.h>

#define RADIUS 8
#define LR 256
#define NC 24
#define GF_EPS 1e-4f

typedef float f4 __attribute__((ext_vector_type(4)));  // native vector: nontemporal-builtin legal

// ---------------- Kernel G: fully fused guided filter, round-2 retry with fixes ----
// One block per (img, PAIR of LR rows k,k+1) -> 8 HR rows. grid = NC*128 = 3072.
// Each block RECOMPUTES the 4 A,B source rows it needs (rows clamp(k-1..k+2)) straight
// from I_lr/p_lr. The 8 I_hr float4 nontemporal loads are issued FIRST so the LR
// recompute runs while HBM reads are in flight.
// Round-2 fixes (counter-diagnosed):
//  * NO min-waves launch_bounds cap: round 2's (256,4) forced VGPR=64 and spilled
//    ih[8] to scratch -> 440 MB of spill WRITE. Default cap lets ~90-110 VGPR live.
//  * Bijective XCD swizzle chunk=384: each XCD owns 3 images -> 1.5 MB LR working set
//    inside its 4 MiB L2; round 2's unswizzled grid fetched 327 MB from HBM.
// LDS 16 KB: tap double-buffer aliased into av[0..7] (barrier-separated), then av/bv
// hold the 8 vertically-lerped phase rows.
__global__ __launch_bounds__(256) void kG(const float* __restrict__ p,
                                          const float* __restrict__ I,
                                          const float* __restrict__ Ihr,
                                          float* __restrict__ out) {
    __shared__ float av[8][LR];
    __shared__ float bv[8][LR];

    const int swz = ((blockIdx.x & 7) * 384) + (blockIdx.x >> 3);  // bijective: 3072%8==0
    const int img = swz >> 7;          // /128
    const int k2  = swz & 127;
    const int k   = k2 << 1;
    const int tx  = threadIdx.x;
    const int ib  = img * LR * LR;
    const float* Ii = I + ib;
    const float* pi = p + ib;

    // --- issue all 8 I_hr vector loads up-front: 128 B/thread in flight under recompute
    // HR row 4k has offset (4k)<<10 = k<<12 within the image.
    const long long base = ((long long)img << 20) + ((long long)k << 12) + (tx << 2);
    f4 ih[8];
    #pragma unroll
    for (int r = 0; r < 8; ++r)
        ih[r] = __builtin_nontemporal_load((const f4*)(Ihr + base + ((long long)r << 10)));

    // --- recompute A,B rows rows[j] = clamp(k-1+j, 0, 255), j=0..3 -----------------
    // vertical running window in registers; horizontal 17-tap via LDS (aliased in av)
    const int r0 = max(k - 1, 0);
    float sI = 0.f, sp_ = 0.f, sIp = 0.f, sII = 0.f;
    #pragma unroll 1
    for (int yy = r0 - RADIUS; yy <= r0 + RADIUS; ++yy) {
        if (yy >= 0 && yy < LR) {
            const float vi = Ii[yy * LR + tx];
            const float vq = pi[yy * LR + tx];
            sI += vi; sp_ += vq; sIp += vi * vq; sII += vi * vi;
        }
    }
    const int cntx = min(tx + RADIUS, LR - 1) - max(tx - RADIUS, 0) + 1;

    float a_[4], b_[4];
    int yprev = r0;
    #pragma unroll
    for (int j = 0; j < 4; ++j) {
        const int y = min(max(k - 1 + j, 0), LR - 1);
        if (y != yprev) {              // block-uniform; slides by exactly one row
            const int yadd = y + RADIUS;
            const int ysub = yprev - RADIUS;
            if (yadd < LR) {
                const float aI = Ii[yadd * LR + tx], aq = pi[yadd * LR + tx];
                sI += aI; sp_ += aq; sIp += aI * aq; sII += aI * aI;
            }
            if (ysub >= 0) {
                const float rI = Ii[ysub * LR + tx], rq = pi[ysub * LR + tx];
                sI -= rI; sp_ -= rq; sIp -= rI * rq; sII -= rI * rI;
            }
        }
        yprev = y;
        // tap staging aliased into av: rows {0,1}=vI {2,3}=vp {4,5}=vIp {6,7}=vII
        const int buf = j & 1;
        av[0 + buf][tx] = sI;
        av[2 + buf][tx] = sp_;
        av[4 + buf][tx] = sIp;
        av[6 + buf][tx] = sII;
        __syncthreads();
        // buf[j&1] is rewritten at j+2, which is after sync(j+1) -> race-free
        float hI = 0.f, hp = 0.f, hIp = 0.f, hII = 0.f;
        #pragma unroll
        for (int t = -RADIUS; t <= RADIUS; ++t) {
            const int   xt = tx + t;
            const int   xx = min(max(xt, 0), LR - 1);
            const float m  = ((unsigned)xt < (unsigned)LR) ? 1.f : 0.f;  // truncated window
            hI  = fmaf(m, av[0 + buf][xx], hI);
            hp  = fmaf(m, av[2 + buf][xx], hp);
            hIp = fmaf(m, av[4 + buf][xx], hIp);
            hII = fmaf(m, av[6 + buf][xx], hII);
        }
        const int   cnty = min(y + RADIUS, LR - 1) - max(y - RADIUS, 0) + 1;
        const float inv  = 1.0f / (float)(cntx * cnty);
        const float mI   = hI * inv;
        const float mp   = hp * inv;
        const float cov  = hIp * inv - mI * mp;
        const float var  = hII * inv - mI * mI;
        a_[j] = cov / (var + GF_EPS);
        b_[j] = mp - a_[j] * mI;
    }
    __syncthreads();   // all tap reads complete before av/bv are overwritten

    // --- vertical bilinear lerps (phase table), written once to LDS ----------------
    // a_[0]=row k-1(cl), a_[1]=row k, a_[2]=row k+1, a_[3]=row k+2(cl)
    av[0][tx] = a_[0] + 0.625f * (a_[1] - a_[0]);
    av[1][tx] = a_[0] + 0.875f * (a_[1] - a_[0]);
    av[2][tx] = a_[1] + 0.125f * (a_[2] - a_[1]);
    av[3][tx] = a_[1] + 0.375f * (a_[2] - a_[1]);
    av[4][tx] = a_[1] + 0.625f * (a_[2] - a_[1]);
    av[5][tx] = a_[1] + 0.875f * (a_[2] - a_[1]);
    av[6][tx] = a_[2] + 0.125f * (a_[3] - a_[2]);
    av[7][tx] = a_[2] + 0.375f * (a_[3] - a_[2]);
    bv[0][tx] = b_[0] + 0.625f * (b_[1] - b_[0]);
    bv[1][tx] = b_[0] + 0.875f * (b_[1] - b_[0]);
    bv[2][tx] = b_[1] + 0.125f * (b_[2] - b_[1]);
    bv[3][tx] = b_[1] + 0.375f * (b_[2] - b_[1]);
    bv[4][tx] = b_[1] + 0.625f * (b_[2] - b_[1]);
    bv[5][tx] = b_[1] + 0.875f * (b_[2] - b_[1]);
    bv[6][tx] = b_[2] + 0.125f * (b_[3] - b_[2]);
    bv[7][tx] = b_[2] + 0.375f * (b_[3] - b_[2]);
    __syncthreads();

    // --- horizontal lerps + fused A*I_hr + B, streamed out -------------------------
    const int cm1 = max(tx - 1, 0);
    const int cp1 = min(tx + 1, LR - 1);

    #pragma unroll
    for (int r = 0; r < 8; ++r) {
        const float am = av[r][cm1], ac = av[r][tx], ap = av[r][cp1];
        const float bm = bv[r][cm1], bc = bv[r][tx], bp = bv[r][cp1];
        float p0, p1, q0, q1;
        if (tx == 0) { p0 = ac; p1 = ac; q0 = bc; q1 = bc; }  // x<0 clamps to col 0
        else {
            p0 = am + 0.625f * (ac - am);
            p1 = am + 0.875f * (ac - am);
            q0 = bm + 0.625f * (bc - bm);
            q1 = bm + 0.875f * (bc - bm);
        }
        const float p2 = ac + 0.125f * (ap - ac);   // tx==255: ap==ac -> clamp ok
        const float p3 = ac + 0.375f * (ap - ac);
        const float q2 = bc + 0.125f * (bp - bc);
        const float q3 = bc + 0.375f * (bp - bc);

        f4 res;
        res.x = p0 * ih[r].x + q0;
        res.y = p1 * ih[r].y + q1;
        res.z = p2 * ih[r].z + q2;
        res.w = p3 * ih[r].w + q3;
        __builtin_nontemporal_store(res, (f4*)(out + base + ((long long)r << 10)));
    }
}

extern "C" void kernel_launch(void* const* d_in, const int* in_sizes, int n_in,
                              void* d_out, int out_size, void* d_ws, size_t ws_size,
                              hipStream_t stream) {
    const float* p_lr = (const float*)d_in[0];
    const float* I_lr = (const float*)d_in[1];
    const float* I_hr = (const float*)d_in[2];
    float* out = (float*)d_out;
    (void)d_ws; (void)ws_size;

    kG<<<NC * 128, 256, 0, stream>>>(p_lr, I_lr, I_hr, out);
}

// Round 6
// 213.037 us; speedup vs baseline: 1.3239x; 1.3239x over previous
//
#include <hip/hip_runtime.h>

#define RADIUS 8
#define LR 256
#define HRES 1024
#define NC 24
#define GF_EPS 1e-4f
#define FSTRIP 8   // output rows per block: grid = NC * (256/8) = 768 blocks

typedef float f4 __attribute__((ext_vector_type(4)));  // native vector: nontemporal-builtin legal

// ---------------- Kernel F: fused LR stage (vertical running sums + horizontal 17-tap + algebra)
// One block per (img, 8-row strip), 256 threads = one per column.
// Vertical box window is a per-thread register running sum; all 8 rows of the 4
// vertical-sum planes are staged to 32 KB LDS, then ONE barrier, then 8 tap-loops.
// XCD swizzle: each XCD owns 3 consecutive images -> 1.5 MB working set in 4 MiB L2.
__global__ __launch_bounds__(256) void kF(const float* __restrict__ p,
                                          const float* __restrict__ I,
                                          float* __restrict__ A, float* __restrict__ B) {
    __shared__ float s[FSTRIP][4][LR];   // [row][quantity: I,p,Ip,II][col] = 32 KB
    const int swz   = ((blockIdx.x & 7) * 96) + (blockIdx.x >> 3);  // bijective: 768%8==0
    const int x     = threadIdx.x;
    const int img   = swz >> 5;          // / 32 strips
    const int strip = swz & 31;
    const int y0    = strip * FSTRIP;
    const int ib    = img * LR * LR;
    const float* Ii = I + ib;
    const float* pi = p + ib;

    // warm-up: vertical sums over rows [y0-8, y0+8] (truncated at edges)
    float sI = 0.f, sp_ = 0.f, sIp = 0.f, sII = 0.f;
    #pragma unroll 1
    for (int yy = y0 - RADIUS; yy <= y0 + RADIUS; ++yy) {
        if (yy >= 0 && yy < LR) {
            const float vi = Ii[yy * LR + x];
            const float vq = pi[yy * LR + x];
            sI  += vi;
            sp_ += vq;
            sIp += vi * vq;
            sII += vi * vi;
        }
    }

    // stage all 8 rows' vertical sums, sliding the register window between rows
    #pragma unroll
    for (int k = 0; k < FSTRIP; ++k) {
        s[k][0][x] = sI;
        s[k][1][x] = sp_;
        s[k][2][x] = sIp;
        s[k][3][x] = sII;
        const int y    = y0 + k;
        const int yadd = y + RADIUS + 1;
        const int ysub = y - RADIUS;
        if (yadd < LR) {
            const float aI = Ii[yadd * LR + x], aq = pi[yadd * LR + x];
            sI += aI; sp_ += aq; sIp += aI * aq; sII += aI * aI;
        }
        if (ysub >= 0) {
            const float rI = Ii[ysub * LR + x], rq = pi[ysub * LR + x];
            sI -= rI; sp_ -= rq; sIp -= rI * rq; sII -= rI * rI;
        }
    }
    __syncthreads();   // the ONLY barrier

    const int cntx = min(x + RADIUS, LR - 1) - max(x - RADIUS, 0) + 1;
    #pragma unroll
    for (int k = 0; k < FSTRIP; ++k) {
        // horizontal 17-tap over the staged vertical sums (stride-1 LDS: conflict-free)
        float hI = 0.f, hp = 0.f, hIp = 0.f, hII = 0.f;
        #pragma unroll
        for (int t = -RADIUS; t <= RADIUS; ++t) {
            const int   xt = x + t;
            const int   xx = min(max(xt, 0), LR - 1);
            const float m  = ((unsigned)xt < (unsigned)LR) ? 1.f : 0.f;  // truncated window
            hI  = fmaf(m, s[k][0][xx], hI);
            hp  = fmaf(m, s[k][1][xx], hp);
            hIp = fmaf(m, s[k][2][xx], hIp);
            hII = fmaf(m, s[k][3][xx], hII);
        }
        const int   y    = y0 + k;
        const int   cnty = min(y + RADIUS, LR - 1) - max(y - RADIUS, 0) + 1;
        const float inv  = 1.0f / (float)(cntx * cnty);
        const float mI   = hI * inv;
        const float mp   = hp * inv;
        const float cov  = hIp * inv - mI * mp;
        const float var  = hII * inv - mI * mI;
        const float a    = cov / (var + GF_EPS);
        const float bb   = mp - a * mI;
        const int   idx  = ib + y * LR + x;
        A[idx] = a;
        B[idx] = bb;
    }
}

// ---------------- Kernel R: bilinear x4 upsample of A,B fused with A*I_hr + B -----
// One block per (img, PAIR of LR rows k,k+1) -> 8 HR rows. grid = NC*128 = 3072.
// ROUND-6 CHANGE (the only one): I_hr loads are REGULAR (cacheable), not nontemporal.
// Round-5 counters showed I_hr is ~half L3-resident across iterations even WITH nt
// loads (FETCH 55 MB vs 100.7 MB I_hr); I_hr(100.7) + out(100.7, nt-stored so it
// doesn't compete) fit in the 256 MB L3. Cacheable loads let warm iterations read
// I_hr from L3 instead of HBM. Output stores stay nontemporal.
__global__ __launch_bounds__(256) void kR(const float* __restrict__ A, const float* __restrict__ B,
                                          const float* __restrict__ Ihr, float* __restrict__ out) {
    __shared__ float av[8][LR];
    __shared__ float bv[8][LR];

    const int swz = ((blockIdx.x & 7) * 384) + (blockIdx.x >> 3);  // bijective: 3072%8==0
    const int img = swz >> 7;          // /128
    const int k2  = swz & 127;
    const int k   = k2 << 1;
    const int tx  = threadIdx.x;

    const float* Ai = A + img * LR * LR;
    const float* Bi = B + img * LR * LR;
    const int rm = max(k - 1, 0);
    const int rp = min(k + 2, LR - 1);

    const float aU = Ai[rm * LR + tx];        // row k-1 (clamped)
    const float a0 = Ai[k * LR + tx];         // row k
    const float a1 = Ai[(k + 1) * LR + tx];   // row k+1
    const float aD = Ai[rp * LR + tx];        // row k+2 (clamped)
    const float bU = Bi[rm * LR + tx];
    const float b0 = Bi[k * LR + tx];
    const float b1 = Bi[(k + 1) * LR + tx];
    const float bD = Bi[rp * LR + tx];

    av[0][tx] = aU + 0.625f * (a0 - aU);
    av[1][tx] = aU + 0.875f * (a0 - aU);
    av[2][tx] = a0 + 0.125f * (a1 - a0);
    av[3][tx] = a0 + 0.375f * (a1 - a0);
    av[4][tx] = a0 + 0.625f * (a1 - a0);
    av[5][tx] = a0 + 0.875f * (a1 - a0);
    av[6][tx] = a1 + 0.125f * (aD - a1);
    av[7][tx] = a1 + 0.375f * (aD - a1);
    bv[0][tx] = bU + 0.625f * (b0 - bU);
    bv[1][tx] = bU + 0.875f * (b0 - bU);
    bv[2][tx] = b0 + 0.125f * (b1 - b0);
    bv[3][tx] = b0 + 0.375f * (b1 - b0);
    bv[4][tx] = b0 + 0.625f * (b1 - b0);
    bv[5][tx] = b0 + 0.875f * (b1 - b0);
    bv[6][tx] = b1 + 0.125f * (bD - b1);
    bv[7][tx] = b1 + 0.375f * (bD - b1);
    __syncthreads();

    // HR row 4k has offset (4k)<<10 = k<<12 within the image.
    const long long base = ((long long)img << 20) + ((long long)k << 12) + (tx << 2);

    f4 ih[8];
    #pragma unroll
    for (int r = 0; r < 8; ++r)
        ih[r] = *(const f4*)(Ihr + base + ((long long)r << 10));   // cacheable: L3-retained

    const int cm1 = max(tx - 1, 0);
    const int cp1 = min(tx + 1, LR - 1);

    #pragma unroll
    for (int r = 0; r < 8; ++r) {
        const float am = av[r][cm1], ac = av[r][tx], ap = av[r][cp1];
        const float bm = bv[r][cm1], bc = bv[r][tx], bp = bv[r][cp1];
        float p0, p1, q0, q1;
        if (tx == 0) { p0 = ac; p1 = ac; q0 = bc; q1 = bc; }  // x<0 clamps to col 0
        else {
            p0 = am + 0.625f * (ac - am);
            p1 = am + 0.875f * (ac - am);
            q0 = bm + 0.625f * (bc - bm);
            q1 = bm + 0.875f * (bc - bm);
        }
        const float p2 = ac + 0.125f * (ap - ac);   // tx==255: ap==ac -> clamp ok
        const float p3 = ac + 0.375f * (ap - ac);
        const float q2 = bc + 0.125f * (bp - bc);
        const float q3 = bc + 0.375f * (bp - bc);

        f4 res;
        res.x = p0 * ih[r].x + q0;
        res.y = p1 * ih[r].y + q1;
        res.z = p2 * ih[r].z + q2;
        res.w = p3 * ih[r].w + q3;
        __builtin_nontemporal_store(res, (f4*)(out + base + ((long long)r << 10)));
    }
}

extern "C" void kernel_launch(void* const* d_in, const int* in_sizes, int n_in,
                              void* d_out, int out_size, void* d_ws, size_t ws_size,
                              hipStream_t stream) {
    const float* p_lr = (const float*)d_in[0];
    const float* I_lr = (const float*)d_in[1];
    const float* I_hr = (const float*)d_in[2];
    float* out = (float*)d_out;
    float* ws  = (float*)d_ws;

    const int S = NC * LR * LR;   // 1,572,864 floats per plane
    float* A = ws + 0 * (size_t)S;
    float* B = ws + 1 * (size_t)S;

    kF<<<NC * (LR / FSTRIP), 256, 0, stream>>>(p_lr, I_lr, A, B);
    kR<<<NC * 128, 256, 0, stream>>>(A, B, I_hr, out);
}

// Round 7
// 210.541 us; speedup vs baseline: 1.3396x; 1.0119x over previous
//
#include <hip/hip_runtime.h>

#define RADIUS 8
#define LR 256
#define HRES 1024
#define NC 24
#define GF_EPS 1e-4f
#define FSTRIP 8   // output rows per block: grid = NC * (256/8) = 768 blocks

typedef float f4 __attribute__((ext_vector_type(4)));  // native vector: nontemporal-builtin legal

// ---------------- Kernel F: fused LR stage (vertical running sums + horizontal 17-tap + algebra)
// One block per (img, 8-row strip), 256 threads = one per column. UNCHANGED from round 6.
__global__ __launch_bounds__(256) void kF(const float* __restrict__ p,
                                          const float* __restrict__ I,
                                          float* __restrict__ A, float* __restrict__ B) {
    __shared__ float s[FSTRIP][4][LR];   // [row][quantity: I,p,Ip,II][col] = 32 KB
    const int swz   = ((blockIdx.x & 7) * 96) + (blockIdx.x >> 3);  // bijective: 768%8==0
    const int x     = threadIdx.x;
    const int img   = swz >> 5;          // / 32 strips
    const int strip = swz & 31;
    const int y0    = strip * FSTRIP;
    const int ib    = img * LR * LR;
    const float* Ii = I + ib;
    const float* pi = p + ib;

    // warm-up: vertical sums over rows [y0-8, y0+8] (truncated at edges)
    float sI = 0.f, sp_ = 0.f, sIp = 0.f, sII = 0.f;
    #pragma unroll 1
    for (int yy = y0 - RADIUS; yy <= y0 + RADIUS; ++yy) {
        if (yy >= 0 && yy < LR) {
            const float vi = Ii[yy * LR + x];
            const float vq = pi[yy * LR + x];
            sI  += vi;
            sp_ += vq;
            sIp += vi * vq;
            sII += vi * vi;
        }
    }

    // stage all 8 rows' vertical sums, sliding the register window between rows
    #pragma unroll
    for (int k = 0; k < FSTRIP; ++k) {
        s[k][0][x] = sI;
        s[k][1][x] = sp_;
        s[k][2][x] = sIp;
        s[k][3][x] = sII;
        const int y    = y0 + k;
        const int yadd = y + RADIUS + 1;
        const int ysub = y - RADIUS;
        if (yadd < LR) {
            const float aI = Ii[yadd * LR + x], aq = pi[yadd * LR + x];
            sI += aI; sp_ += aq; sIp += aI * aq; sII += aI * aI;
        }
        if (ysub >= 0) {
            const float rI = Ii[ysub * LR + x], rq = pi[ysub * LR + x];
            sI -= rI; sp_ -= rq; sIp -= rI * rq; sII -= rI * rI;
        }
    }
    __syncthreads();   // the ONLY barrier

    const int cntx = min(x + RADIUS, LR - 1) - max(x - RADIUS, 0) + 1;
    #pragma unroll
    for (int k = 0; k < FSTRIP; ++k) {
        // horizontal 17-tap over the staged vertical sums (stride-1 LDS: conflict-free)
        float hI = 0.f, hp = 0.f, hIp = 0.f, hII = 0.f;
        #pragma unroll
        for (int t = -RADIUS; t <= RADIUS; ++t) {
            const int   xt = x + t;
            const int   xx = min(max(xt, 0), LR - 1);
            const float m  = ((unsigned)xt < (unsigned)LR) ? 1.f : 0.f;  // truncated window
            hI  = fmaf(m, s[k][0][xx], hI);
            hp  = fmaf(m, s[k][1][xx], hp);
            hIp = fmaf(m, s[k][2][xx], hIp);
            hII = fmaf(m, s[k][3][xx], hII);
        }
        const int   y    = y0 + k;
        const int   cnty = min(y + RADIUS, LR - 1) - max(y - RADIUS, 0) + 1;
        const float inv  = 1.0f / (float)(cntx * cnty);
        const float mI   = hI * inv;
        const float mp   = hp * inv;
        const float cov  = hIp * inv - mI * mp;
        const float var  = hII * inv - mI * mI;
        const float a    = cov / (var + GF_EPS);
        const float bb   = mp - a * mI;
        const int   idx  = ib + y * LR + x;
        A[idx] = a;
        B[idx] = bb;
    }
}

// ---------------- Kernel R: bilinear x4 upsample of A,B fused with A*I_hr + B -----
// One block per (img, PAIR of LR rows k,k+1) -> 8 HR rows. grid = NC*128 = 3072.
// ROUND-7 RESTRUCTURE (counter-diagnosed: 60us @ 2.6TB/s, VALUBusy 6%, Occ 57% ->
// latency/occupancy-bound, not BW-bound):
//  * LDS 16KB -> 8KB: stage the 4 RAW A,B rows; vertical phase lerps move to
//    registers (VALU is idle). LDS no longer caps blocks/CU (was 10 vs 12 wanted).
//  * The 8 I_hr loads are issued BEFORE the A/B loads and the barrier -- their HBM
//    latency hides under the A/B fetch + staging + barrier (compiler cannot hoist
//    global loads across __syncthreads, so program order matters).
// Phase table (HR row 8*k2+r): row j0/j1 indices into raw rows {k-1,k,k+1,k+2}(cl):
//   r: 0    1    2    3    4    5    6    7
//  j0: 0    0    1    1    1    1    2    2
//  j1: 1    1    2    2    2    2    3    3
//   f: .625 .875 .125 .375 .625 .875 .125 .375
__global__ __launch_bounds__(256) void kR(const float* __restrict__ A, const float* __restrict__ B,
                                          const float* __restrict__ Ihr, float* __restrict__ out) {
    __shared__ float sa[4][LR];
    __shared__ float sb[4][LR];

    const int swz = ((blockIdx.x & 7) * 384) + (blockIdx.x >> 3);  // bijective: 3072%8==0
    const int img = swz >> 7;          // /128
    const int k2  = swz & 127;
    const int k   = k2 << 1;
    const int tx  = threadIdx.x;

    // --- issue all 8 I_hr vector loads FIRST: 128 B/thread in flight under staging
    // HR row 4k has offset (4k)<<10 = k<<12 within the image.
    const long long base = ((long long)img << 20) + ((long long)k << 12) + (tx << 2);
    f4 ih[8];
    #pragma unroll
    for (int r = 0; r < 8; ++r)
        ih[r] = *(const f4*)(Ihr + base + ((long long)r << 10));

    // --- load 4 raw A,B rows (L2/L3-resident, 12.6 MB total) and stage to 8 KB LDS
    const float* Ai = A + img * LR * LR;
    const float* Bi = B + img * LR * LR;
    const int rm = max(k - 1, 0);
    const int rp = min(k + 2, LR - 1);

    float ac_[4], bc_[4];
    ac_[0] = Ai[rm * LR + tx];        // row k-1 (clamped)
    ac_[1] = Ai[k * LR + tx];         // row k
    ac_[2] = Ai[(k + 1) * LR + tx];   // row k+1
    ac_[3] = Ai[rp * LR + tx];        // row k+2 (clamped)
    bc_[0] = Bi[rm * LR + tx];
    bc_[1] = Bi[k * LR + tx];
    bc_[2] = Bi[(k + 1) * LR + tx];
    bc_[3] = Bi[rp * LR + tx];

    #pragma unroll
    for (int j = 0; j < 4; ++j) { sa[j][tx] = ac_[j]; sb[j][tx] = bc_[j]; }
    __syncthreads();

    // --- neighbor columns from LDS into registers (16 reads), then all-register math
    const int cm1 = max(tx - 1, 0);
    const int cp1 = min(tx + 1, LR - 1);
    float am_[4], ap_[4], bm_[4], bp_[4];
    #pragma unroll
    for (int j = 0; j < 4; ++j) {
        am_[j] = sa[j][cm1];
        ap_[j] = sa[j][cp1];
        bm_[j] = sb[j][cm1];
        bp_[j] = sb[j][cp1];
    }

    const int   J0[8] = {0, 0, 1, 1, 1, 1, 2, 2};
    const int   J1[8] = {1, 1, 2, 2, 2, 2, 3, 3};
    const float FR[8] = {0.625f, 0.875f, 0.125f, 0.375f, 0.625f, 0.875f, 0.125f, 0.375f};

    #pragma unroll
    for (int r = 0; r < 8; ++r) {      // full unroll: J0/J1/FR fold to compile-time consts
        const int   j0 = J0[r], j1 = J1[r];
        const float f  = FR[r];
        const float ac = ac_[j0] + f * (ac_[j1] - ac_[j0]);   // vertical lerp, registers
        const float am = am_[j0] + f * (am_[j1] - am_[j0]);
        const float ap = ap_[j0] + f * (ap_[j1] - ap_[j0]);
        const float bc = bc_[j0] + f * (bc_[j1] - bc_[j0]);
        const float bm = bm_[j0] + f * (bm_[j1] - bm_[j0]);
        const float bp = bp_[j0] + f * (bp_[j1] - bp_[j0]);

        float p0, p1, q0, q1;
        if (tx == 0) { p0 = ac; p1 = ac; q0 = bc; q1 = bc; }  // x<0 clamps to col 0
        else {
            p0 = am + 0.625f * (ac - am);
            p1 = am + 0.875f * (ac - am);
            q0 = bm + 0.625f * (bc - bm);
            q1 = bm + 0.875f * (bc - bm);
        }
        const float p2 = ac + 0.125f * (ap - ac);   // tx==255: ap==ac -> clamp ok
        const float p3 = ac + 0.375f * (ap - ac);
        const float q2 = bc + 0.125f * (bp - bc);
        const float q3 = bc + 0.375f * (bp - bc);

        f4 res;
        res.x = p0 * ih[r].x + q0;
        res.y = p1 * ih[r].y + q1;
        res.z = p2 * ih[r].z + q2;
        res.w = p3 * ih[r].w + q3;
        __builtin_nontemporal_store(res, (f4*)(out + base + ((long long)r << 10)));
    }
}

extern "C" void kernel_launch(void* const* d_in, const int* in_sizes, int n_in,
                              void* d_out, int out_size, void* d_ws, size_t ws_size,
                              hipStream_t stream) {
    const float* p_lr = (const float*)d_in[0];
    const float* I_lr = (const float*)d_in[1];
    const float* I_hr = (const float*)d_in[2];
    float* out = (float*)d_out;
    float* ws  = (float*)d_ws;

    const int S = NC * LR * LR;   // 1,572,864 floats per plane
    float* A = ws + 0 * (size_t)S;
    float* B = ws + 1 * (size_t)S;

    kF<<<NC * (LR / FSTRIP), 256, 0, stream>>>(p_lr, I_lr, A, B);
    kR<<<NC * 128, 256, 0, stream>>>(A, B, I_hr, out);
}

// Round 9
// 200.509 us; speedup vs baseline: 1.4066x; 1.0500x over previous
//
#include <hip/hip_runtime.h>

#define RADIUS 8
#define LR 256
#define HRES 1024
#define NC 24
#define GF_EPS 1e-4f
#define FSTRIP 4   // output rows per block: grid = NC * (256/4) = 1536 blocks (6/CU)

typedef float f4 __attribute__((ext_vector_type(4)));  // native vector: nontemporal-builtin legal

// ---------------- Kernel F: fused LR stage, round-8 rewrite --------------------
// Counter-driven theory: old kF was vmcnt-serialized (unroll-1 warm-up: 17 dependent
// load->wait->fma round-trips) and under-parallel (768 blocks = 3/CU). Fixes:
//  * branchless clamped-address loads + float mask, FULL unroll: all 34 warm-up
//    loads issue back-to-back with one wait instead of 17 serial L2 round-trips.
//  * FSTRIP 8->4: 1536 blocks = 6/CU, LDS 16 KB. Edge re-reads are L2-local under
//    the chunk=192 bijective XCD swizzle (3 images/XCD = 1.5 MB in 4 MiB L2).
__global__ __launch_bounds__(256) void kF(const float* __restrict__ p,
                                          const float* __restrict__ I,
                                          float* __restrict__ A, float* __restrict__ B) {
    __shared__ float s[FSTRIP][4][LR];   // [row][quantity: I,p,Ip,II][col] = 16 KB
    const int swz   = ((blockIdx.x & 7) * 192) + (blockIdx.x >> 3);  // bijective: 1536%8==0
    const int x     = threadIdx.x;
    const int img   = swz >> 6;          // / 64 strips
    const int strip = swz & 63;
    const int y0    = strip * FSTRIP;
    const int ib    = img * LR * LR;
    const float* Ii = I + ib;
    const float* pi = p + ib;

    // warm-up: vertical sums over rows [y0-8, y0+8] — branchless, fully unrolled:
    // clamped addresses are always valid, mask zeroes out-of-range rows, so the
    // compiler issues all 34 loads before the first accumulation wait.
    float sI = 0.f, sp_ = 0.f, sIp = 0.f, sII = 0.f;
    #pragma unroll
    for (int t = -RADIUS; t <= RADIUS; ++t) {
        const int   yy = y0 + t;
        const int   yc = min(max(yy, 0), LR - 1);
        const float m  = ((unsigned)yy < (unsigned)LR) ? 1.f : 0.f;
        const float vi = Ii[yc * LR + x];
        const float vq = pi[yc * LR + x];
        const float vim = m * vi;
        sI  += vim;
        sp_  = fmaf(m, vq, sp_);
        sIp  = fmaf(vim, vq, sIp);
        sII  = fmaf(vim, vi, sII);
    }

    // stage FSTRIP rows' vertical sums, branchless masked slides (fully unrolled)
    #pragma unroll
    for (int k = 0; k < FSTRIP; ++k) {
        s[k][0][x] = sI;
        s[k][1][x] = sp_;
        s[k][2][x] = sIp;
        s[k][3][x] = sII;
        const int   ya  = y0 + k + RADIUS + 1;
        const int   ys  = y0 + k - RADIUS;
        const int   yac = min(ya, LR - 1);
        const int   ysc = max(ys, 0);
        const float ma  = (ya < LR) ? 1.f : 0.f;
        const float ms  = (ys >= 0) ? 1.f : 0.f;
        const float aI = Ii[yac * LR + x], aq = pi[yac * LR + x];
        const float rI = Ii[ysc * LR + x], rq = pi[ysc * LR + x];
        const float aIm = ma * aI, rIm = ms * rI;
        sI  += aIm - rIm;
        sp_ += ma * aq - ms * rq;
        sIp += aIm * aq - rIm * rq;
        sII += aIm * aI - rIm * rI;
    }
    __syncthreads();   // the ONLY barrier

    const int cntx = min(x + RADIUS, LR - 1) - max(x - RADIUS, 0) + 1;
    #pragma unroll
    for (int k = 0; k < FSTRIP; ++k) {
        // horizontal 17-tap over the staged vertical sums (stride-1 LDS: conflict-free)
        float hI = 0.f, hp = 0.f, hIp = 0.f, hII = 0.f;
        #pragma unroll
        for (int t = -RADIUS; t <= RADIUS; ++t) {
            const int   xt = x + t;
            const int   xx = min(max(xt, 0), LR - 1);
            const float m  = ((unsigned)xt < (unsigned)LR) ? 1.f : 0.f;  // truncated window
            hI  = fmaf(m, s[k][0][xx], hI);
            hp  = fmaf(m, s[k][1][xx], hp);
            hIp = fmaf(m, s[k][2][xx], hIp);
            hII = fmaf(m, s[k][3][xx], hII);
        }
        const int   y    = y0 + k;
        const int   cnty = min(y + RADIUS, LR - 1) - max(y - RADIUS, 0) + 1;
        const float inv  = 1.0f / (float)(cntx * cnty);
        const float mI   = hI * inv;
        const float mp   = hp * inv;
        const float cov  = hIp * inv - mI * mp;
        const float var  = hII * inv - mI * mI;
        const float a    = cov / (var + GF_EPS);
        const float bb   = mp - a * mI;
        const int   idx  = ib + y * LR + x;
        A[idx] = a;
        B[idx] = bb;
    }
}

// ---------------- Kernel R: bilinear x4 upsample of A,B fused with A*I_hr + B -----
// One block per (img, PAIR of LR rows k,k+1) -> 8 HR rows. grid = NC*128 = 3072.
// UNCHANGED from round 7 (8 KB LDS, I_hr loads issued before the barrier).
// Phase table (HR row 8*k2+r): row j0/j1 indices into raw rows {k-1,k,k+1,k+2}(cl):
//   r: 0    1    2    3    4    5    6    7
//  j0: 0    0    1    1    1    1    2    2
//  j1: 1    1    2    2    2    2    3    3
//   f: .625 .875 .125 .375 .625 .875 .125 .375
__global__ __launch_bounds__(256) void kR(const float* __restrict__ A, const float* __restrict__ B,
                                          const float* __restrict__ Ihr, float* __restrict__ out) {
    __shared__ float sa[4][LR];
    __shared__ float sb[4][LR];

    const int swz = ((blockIdx.x & 7) * 384) + (blockIdx.x >> 3);  // bijective: 3072%8==0
    const int img = swz >> 7;          // /128
    const int k2  = swz & 127;
    const int k   = k2 << 1;
    const int tx  = threadIdx.x;

    // --- issue all 8 I_hr vector loads FIRST: 128 B/thread in flight under staging
    // HR row 4k has offset (4k)<<10 = k<<12 within the image.
    const long long base = ((long long)img << 20) + ((long long)k << 12) + (tx << 2);
    f4 ih[8];
    #pragma unroll
    for (int r = 0; r < 8; ++r)
        ih[r] = *(const f4*)(Ihr + base + ((long long)r << 10));

    // --- load 4 raw A,B rows (L2/L3-resident, 12.6 MB total) and stage to 8 KB LDS
    const float* Ai = A + img * LR * LR;
    const float* Bi = B + img * LR * LR;
    const int rm = max(k - 1, 0);
    const int rp = min(k + 2, LR - 1);

    float ac_[4], bc_[4];
    ac_[0] = Ai[rm * LR + tx];        // row k-1 (clamped)
    ac_[1] = Ai[k * LR + tx];         // row k
    ac_[2] = Ai[(k + 1) * LR + tx];   // row k+1
    ac_[3] = Ai[rp * LR + tx];        // row k+2 (clamped)
    bc_[0] = Bi[rm * LR + tx];
    bc_[1] = Bi[k * LR + tx];
    bc_[2] = Bi[(k + 1) * LR + tx];
    bc_[3] = Bi[rp * LR + tx];

    #pragma unroll
    for (int j = 0; j < 4; ++j) { sa[j][tx] = ac_[j]; sb[j][tx] = bc_[j]; }
    __syncthreads();

    // --- neighbor columns from LDS into registers (16 reads), then all-register math
    const int cm1 = max(tx - 1, 0);
    const int cp1 = min(tx + 1, LR - 1);
    float am_[4], ap_[4], bm_[4], bp_[4];
    #pragma unroll
    for (int j = 0; j < 4; ++j) {
        am_[j] = sa[j][cm1];
        ap_[j] = sa[j][cp1];
        bm_[j] = sb[j][cm1];
        bp_[j] = sb[j][cp1];
    }

    const int   J0[8] = {0, 0, 1, 1, 1, 1, 2, 2};
    const int   J1[8] = {1, 1, 2, 2, 2, 2, 3, 3};
    const float FR[8] = {0.625f, 0.875f, 0.125f, 0.375f, 0.625f, 0.875f, 0.125f, 0.375f};

    #pragma unroll
    for (int r = 0; r < 8; ++r) {      // full unroll: J0/J1/FR fold to compile-time consts
        const int   j0 = J0[r], j1 = J1[r];
        const float f  = FR[r];
        const float ac = ac_[j0] + f * (ac_[j1] - ac_[j0]);   // vertical lerp, registers
        const float am = am_[j0] + f * (am_[j1] - am_[j0]);
        const float ap = ap_[j0] + f * (ap_[j1] - ap_[j0]);
        const float bc = bc_[j0] + f * (bc_[j1] - bc_[j0]);
        const float bm = bm_[j0] + f * (bm_[j1] - bm_[j0]);
        const float bp = bp_[j0] + f * (bp_[j1] - bp_[j0]);

        float p0, p1, q0, q1;
        if (tx == 0) { p0 = ac; p1 = ac; q0 = bc; q1 = bc; }  // x<0 clamps to col 0
        else {
            p0 = am + 0.625f * (ac - am);
            p1 = am + 0.875f * (ac - am);
            q0 = bm + 0.625f * (bc - bm);
            q1 = bm + 0.875f * (bc - bm);
        }
        const float p2 = ac + 0.125f * (ap - ac);   // tx==255: ap==ac -> clamp ok
        const float p3 = ac + 0.375f * (ap - ac);
        const float q2 = bc + 0.125f * (bp - bc);
        const float q3 = bc + 0.375f * (bp - bc);

        f4 res;
        res.x = p0 * ih[r].x + q0;
        res.y = p1 * ih[r].y + q1;
        res.z = p2 * ih[r].z + q2;
        res.w = p3 * ih[r].w + q3;
        __builtin_nontemporal_store(res, (f4*)(out + base + ((long long)r << 10)));
    }
}

extern "C" void kernel_launch(void* const* d_in, const int* in_sizes, int n_in,
                              void* d_out, int out_size, void* d_ws, size_t ws_size,
                              hipStream_t stream) {
    const float* p_lr = (const float*)d_in[0];
    const float* I_lr = (const float*)d_in[1];
    const float* I_hr = (const float*)d_in[2];
    float* out = (float*)d_out;
    float* ws  = (float*)d_ws;

    const int S = NC * LR * LR;   // 1,572,864 floats per plane
    float* A = ws + 0 * (size_t)S;
    float* B = ws + 1 * (size_t)S;

    kF<<<NC * (LR / FSTRIP), 256, 0, stream>>>(p_lr, I_lr, A, B);
    kR<<<NC * 128, 256, 0, stream>>>(A, B, I_hr, out);
}